// Round 7
// baseline (616.027 us; speedup 1.0000x reference)
//
#include <hip/hip_runtime.h>
#include <math.h>

// Persistent Sinkhorn R7: no-max-shift log2-domain lse + early zero-fill.
//
// R6 post-mortem: fused 296us; VALU 110us, HBM 143us -> still stall-heavy.
// FETCH 503MB showed mh re-fetches from HBM (L3 not retaining); not fixable
// at HIP level. Attack VALU + chain length + tail instead:
//  1. NO max-shift: |m|<=5.7 and potentials bounded (~+-30) -> z in [-40,30],
//     exp2 can't overflow fp32. Removes 16 fmax + 6-shfl wave-max per row
//     AND unserializes the chain (exps issue right after loads).
//  2. log2 domain: mh2 = m*log2e stored fp16; u,v are log2-potentials;
//     v_exp_f32/v_log_f32 are natively 2^x/log2(x) -> drops the *log2e mul
//     inside every __expf and the *ln2 in every __logf.
//  3. Early zero-fill: rows >= nr written right after F0 (overlaps other
//     batches' compute + own barrier wait); nr==0 / nc==0 batches write all
//     zeros and EXIT (batch-consistent; their barrier never touched). Also
//     fixes latent NaN risk (final no longer reads unwritten mh).
// Carried from R3-R6 (proven): per-batch monotonic barrier w/ relaxed agent
// atomics + vmcnt(0) drain; sc0sc1-coherent P only; 1 barrier/iter; plain-sum
// col partials via exp reuse (v_new = v_old - log2 sum p/s); conflict-free
// pbuf[4][64][17] merge; coalesced P layout; dual-row ILP; fp16-final.
//
// ws: bar@0 (4KB) | P@1MB (2 x 4MB) | mh@16MB (128MB). ws >= 1GB.

#define BIGNEG (-1e30f)
#define LOG2E 1.44269504f
typedef _Float16 h16;
struct alignas(16) h8 { h16 h[8]; };

#define NN 1024
#define MM 1024
#define NBLK 16  // blocks per batch

__device__ __forceinline__ float wave_sum64(float v) {
#pragma unroll
    for (int o = 32; o > 0; o >>= 1) v += __shfl_xor(v, o, 64);
    return v;
}

__device__ __forceinline__ float ld_coh(const float* p) {
    return __hip_atomic_load(p, __ATOMIC_RELAXED, __HIP_MEMORY_SCOPE_AGENT);
}
__device__ __forceinline__ void st_coh(float* p, float v) {
    __hip_atomic_store(p, v, __ATOMIC_RELAXED, __HIP_MEMORY_SCOPE_AGENT);
}

__global__ void zero_bar(unsigned* bar, int n) {
    const int i = blockIdx.x * blockDim.x + threadIdx.x;
    if (i < n) bar[i] = 0;
}

// Monotonic per-batch barrier (proven R3-R6). Relaxed atomics; each wave
// drains its own sc1 stores to the coherence point before arriving.
#define BATCH_BAR()                                                            \
    do {                                                                       \
        asm volatile("s_waitcnt vmcnt(0)" ::: "memory");                       \
        __syncthreads();                                                       \
        ++phase;                                                               \
        if (threadIdx.x == 0) {                                                \
            __hip_atomic_fetch_add(ctr, 1u, __ATOMIC_RELAXED,                  \
                                   __HIP_MEMORY_SCOPE_AGENT);                  \
            while (__hip_atomic_load(ctr, __ATOMIC_RELAXED,                    \
                                     __HIP_MEMORY_SCOPE_AGENT) <               \
                   (unsigned)(phase * NBLK))                                   \
                __builtin_amdgcn_s_sleep(8);                                   \
        }                                                                      \
        __syncthreads();                                                       \
        asm volatile("" ::: "memory");                                         \
    } while (0)

// No-shift lse over 16 per-lane log2-domain values: S = sum 2^z (wave-wide),
// u2 = -log2(S); col partials cs[e] += 2^z[e] / S. Safe: |z| << 126.
__device__ __forceinline__ void sum16(const float* z, float* cs, float& u2) {
    float p[16], s = 0.f;
#pragma unroll
    for (int e = 0; e < 16; ++e) {
        p[e] = __builtin_amdgcn_exp2f(z[e]);
        s += p[e];
    }
    s = wave_sum64(s);
    const float rs = __builtin_amdgcn_rcpf(s);
#pragma unroll
    for (int e = 0; e < 16; ++e) cs[e] += p[e] * rs;
    u2 = -__builtin_amdgcn_logf(s);  // v_log_f32 = log2
}

__global__ __launch_bounds__(256, 4) void sinkhorn_fused(
    const float* __restrict__ m, const int* __restrict__ nrows,
    const int* __restrict__ ncols, float* __restrict__ P,
    h16* __restrict__ mh, unsigned* __restrict__ bar, float* __restrict__ out,
    int B) {
    const int sub = blockIdx.x & (NBLK - 1);
    const int b = blockIdx.x >> 4;
    const int w = threadIdx.x >> 6;
    const int lane = threadIdx.x & 63;
    const int wid = sub * 4 + w;  // wave id within batch [0,64)
    const int tid = threadIdx.x;
    const int nr = nrows[b];
    const int nc = ncols[b];
    unsigned* ctr = bar + (size_t)b * 16;
    int phase = 0;

    __shared__ float pbuf[4][64][17];  // 17KB padded: conflict-free merge
    __shared__ float vloc[MM];         // 4KB full v (log2), block-local
    __shared__ float uloc[NN];         // 4KB u (log2) for this block's rows

    const size_t mbo = (size_t)b * NN * MM;
    const float4 z4 = make_float4(0.f, 0.f, 0.f, 0.f);

    // ---- degenerate batches: all-zero output, exit (no barrier contact) ----
    if (nr == 0 || nc == 0) {
        for (int row = wid; row < NN; row += 64) {
            float* orow = out + mbo + (size_t)row * MM + lane * 8;
            *reinterpret_cast<float4*>(orow) = z4;
            *reinterpret_cast<float4*>(orow + 4) = z4;
            *reinterpret_cast<float4*>(orow + 512) = z4;
            *reinterpret_cast<float4*>(orow + 516) = z4;
        }
        return;
    }

    const size_t Psz = (size_t)B * NBLK * MM;  // one parity buffer (4MB)
    float* Pw0 = P + (size_t)b * NBLK * MM + (size_t)sub * MM;
    const float* Pr0 = P + (size_t)b * NBLK * MM;

    float cs[16];
#pragma unroll
    for (int e = 0; e < 16; ++e) cs[e] = 0.f;

    // ---- F0: fp32 m -> fp16 mh2=m*log2e, u1, col partial sums ----
    {
        float mk[16];
#pragma unroll
        for (int e = 0; e < 16; ++e) {
            const int col = lane * 8 + (e >> 3) * 512 + (e & 7);
            mk[e] = (col < nc) ? 0.f : BIGNEG;
        }
        int row = wid;
        float4 A0, A1, A2, A3;
        if (row < nr) {
            const float* rp = m + mbo + (size_t)row * MM + lane * 8;
            A0 = *reinterpret_cast<const float4*>(rp);
            A1 = *reinterpret_cast<const float4*>(rp + 4);
            A2 = *reinterpret_cast<const float4*>(rp + 512);
            A3 = *reinterpret_cast<const float4*>(rp + 516);
        }
        while (row < nr) {
            const int nx = row + 64;
            float4 N0, N1, N2, N3;
            if (nx < nr) {  // prefetch next row while reducing current
                const float* rq = m + mbo + (size_t)nx * MM + lane * 8;
                N0 = *reinterpret_cast<const float4*>(rq);
                N1 = *reinterpret_cast<const float4*>(rq + 4);
                N2 = *reinterpret_cast<const float4*>(rq + 512);
                N3 = *reinterpret_cast<const float4*>(rq + 516);
            }
            float zs[16], zr[16];
            *reinterpret_cast<float4*>(&zs[0]) = A0;
            *reinterpret_cast<float4*>(&zs[4]) = A1;
            *reinterpret_cast<float4*>(&zs[8]) = A2;
            *reinterpret_cast<float4*>(&zs[12]) = A3;
#pragma unroll
            for (int e = 0; e < 16; ++e) {
                zs[e] *= LOG2E;          // log2 domain
                zr[e] = zs[e] + mk[e];   // masked copy for the reduce
            }
            h8 hv0, hv1;
#pragma unroll
            for (int e = 0; e < 8; ++e) hv0.h[e] = (h16)zs[e];
#pragma unroll
            for (int e = 0; e < 8; ++e) hv1.h[e] = (h16)zs[8 + e];
            h16* rh = mh + mbo + (size_t)row * MM + lane * 8;
            *reinterpret_cast<h8*>(rh) = hv0;
            *reinterpret_cast<h8*>(rh + 512) = hv1;
            float u;
            sum16(zr, cs, u);
            if (lane == 0) uloc[row] = u;
            A0 = N0; A1 = N1; A2 = N2; A3 = N3;
            row = nx;
        }
    }

    // ---- early zero-fill of invalid rows (overlaps other batches' work) ----
    for (int row = nr + wid; row < NN; row += 64) {
        float* orow = out + mbo + (size_t)row * MM + lane * 8;
        *reinterpret_cast<float4*>(orow) = z4;
        *reinterpret_cast<float4*>(orow + 4) = z4;
        *reinterpret_cast<float4*>(orow + 512) = z4;
        *reinterpret_cast<float4*>(orow + 516) = z4;
    }

    for (int t = 1; t <= 10; ++t) {
        // ---- merge 4 waves' cs -> block partial -> coherent P[t&1] ----
#pragma unroll
        for (int e = 0; e < 16; ++e) pbuf[w][lane][e] = cs[e];
        __syncthreads();
        {
            float* Pw = Pw0 + (size_t)(t & 1) * Psz;
#pragma unroll
            for (int q = 0; q < 4; ++q) {
                const int col = tid + q * 256;  // coalesced
                const int ls = (col >> 3) & 63;
                const int ei = ((col >> 9) << 3) | (col & 7);
                const float sum = pbuf[0][ls][ei] + pbuf[1][ls][ei] +
                                  pbuf[2][ls][ei] + pbuf[3][ls][ei];
                st_coh(Pw + col, sum);
            }
        }

        BATCH_BAR();  // all 16 blocks' partials at coherence point

        // ---- redundant local finalize: full v (log2) for all 1024 cols ----
        {
            const float* Pr = Pr0 + (size_t)(t & 1) * Psz;
#pragma unroll
            for (int q = 0; q < 4; ++q) {
                const int col = tid + q * 256;  // coalesced
                float CS = 0.f;
#pragma unroll
                for (int s16 = 0; s16 < NBLK; ++s16)
                    CS += ld_coh(Pr + s16 * MM + col);
                const float vp = (t == 1) ? 0.f : vloc[col];
                const float vn = vp - __log2f(CS);  // CS=0 -> +inf -> clamp
                vloc[col] = fminf(fmaxf(vn, BIGNEG), 1e30f);
            }
        }
        __syncthreads();  // vloc ready for all waves
        if (t == 10) break;

        // ---- row pass: u_{t+1} = -lse2_j(mh2+v_t); col sums for v_{t+1} ----
        float vvm[16];
        {
            float tmp[16];
            *reinterpret_cast<float4*>(&tmp[0]) =
                *reinterpret_cast<const float4*>(&vloc[lane * 8]);
            *reinterpret_cast<float4*>(&tmp[4]) =
                *reinterpret_cast<const float4*>(&vloc[lane * 8 + 4]);
            *reinterpret_cast<float4*>(&tmp[8]) =
                *reinterpret_cast<const float4*>(&vloc[lane * 8 + 512]);
            *reinterpret_cast<float4*>(&tmp[12]) =
                *reinterpret_cast<const float4*>(&vloc[lane * 8 + 516]);
#pragma unroll
            for (int e = 0; e < 16; ++e) {
                const int col = lane * 8 + (e >> 3) * 512 + (e & 7);
                vvm[e] = (col < nc) ? tmp[e] : BIGNEG;
            }
        }
#pragma unroll
        for (int e = 0; e < 16; ++e) cs[e] = 0.f;
        {
            int row = wid;
            // dual-row: two independent chains, 4 loads issued first
            while (row + 64 < nr) {
                const h16* r0 = mh + mbo + (size_t)row * MM + lane * 8;
                const h16* r1 = r0 + (size_t)64 * MM;
                const h8 a0 = *reinterpret_cast<const h8*>(r0);
                const h8 a1 = *reinterpret_cast<const h8*>(r0 + 512);
                const h8 b0 = *reinterpret_cast<const h8*>(r1);
                const h8 b1 = *reinterpret_cast<const h8*>(r1 + 512);
                float z0[16], z1[16];
#pragma unroll
                for (int e = 0; e < 8; ++e) {
                    z0[e] = (float)a0.h[e] + vvm[e];
                    z0[8 + e] = (float)a1.h[e] + vvm[8 + e];
                    z1[e] = (float)b0.h[e] + vvm[e];
                    z1[8 + e] = (float)b1.h[e] + vvm[8 + e];
                }
                float u0, u1;
                sum16(z0, cs, u0);
                sum16(z1, cs, u1);
                if (lane == 0) { uloc[row] = u0; uloc[row + 64] = u1; }
                row += 128;
            }
            if (row < nr) {
                const h16* r0 = mh + mbo + (size_t)row * MM + lane * 8;
                const h8 a0 = *reinterpret_cast<const h8*>(r0);
                const h8 a1 = *reinterpret_cast<const h8*>(r0 + 512);
                float z0[16];
#pragma unroll
                for (int e = 0; e < 8; ++e) {
                    z0[e] = (float)a0.h[e] + vvm[e];
                    z0[8 + e] = (float)a1.h[e] + vvm[8 + e];
                }
                float u0;
                sum16(z0, cs, u0);
                if (lane == 0) uloc[row] = u0;
            }
        }
    }

    // ---- final: out = 2^(mh2 + u10 + v10), valid rows only ----
    {
        float vvm[16];
        float tmp[16];
        *reinterpret_cast<float4*>(&tmp[0]) =
            *reinterpret_cast<const float4*>(&vloc[lane * 8]);
        *reinterpret_cast<float4*>(&tmp[4]) =
            *reinterpret_cast<const float4*>(&vloc[lane * 8 + 4]);
        *reinterpret_cast<float4*>(&tmp[8]) =
            *reinterpret_cast<const float4*>(&vloc[lane * 8 + 512]);
        *reinterpret_cast<float4*>(&tmp[12]) =
            *reinterpret_cast<const float4*>(&vloc[lane * 8 + 516]);
#pragma unroll
        for (int e = 0; e < 16; ++e) {
            const int col = lane * 8 + (e >> 3) * 512 + (e & 7);
            vvm[e] = (col < nc) ? tmp[e] : BIGNEG;
        }
        for (int row = wid; row < nr; row += 64) {
            float* orow = out + mbo + (size_t)row * MM + lane * 8;
            const float ui = uloc[row];
            const h16* rh = mh + mbo + (size_t)row * MM + lane * 8;
            const h8 h0 = *reinterpret_cast<const h8*>(rh);
            const h8 h1 = *reinterpret_cast<const h8*>(rh + 512);
            float r[16];
#pragma unroll
            for (int e = 0; e < 8; ++e) {
                r[e] = __builtin_amdgcn_exp2f((float)h0.h[e] + ui + vvm[e]);
                r[8 + e] =
                    __builtin_amdgcn_exp2f((float)h1.h[e] + ui + vvm[8 + e]);
            }
            *reinterpret_cast<float4*>(orow) = *reinterpret_cast<float4*>(&r[0]);
            *reinterpret_cast<float4*>(orow + 4) =
                *reinterpret_cast<float4*>(&r[4]);
            *reinterpret_cast<float4*>(orow + 512) =
                *reinterpret_cast<float4*>(&r[8]);
            *reinterpret_cast<float4*>(orow + 516) =
                *reinterpret_cast<float4*>(&r[12]);
        }
    }
}

extern "C" void kernel_launch(void* const* d_in, const int* in_sizes, int n_in,
                              void* d_out, int out_size, void* d_ws,
                              size_t ws_size, hipStream_t stream) {
    const float* m = (const float*)d_in[0];
    const int* nrows = (const int*)d_in[1];
    const int* ncols = (const int*)d_in[2];
    const int B = in_sizes[1];

    char* ws = (char*)d_ws;
    unsigned* bar = (unsigned*)ws;          // 4KB
    float* P = (float*)(ws + (1u << 20));   // 2 x 4MB
    h16* mh = (h16*)(ws + (16u << 20));     // 128MB
    float* out = (float*)d_out;

    const int nbar = B * 16;
    zero_bar<<<dim3((nbar + 255) / 256), dim3(256), 0, stream>>>(bar, nbar);

    sinkhorn_fused<<<dim3(B * NBLK), dim3(256), 0, stream>>>(
        m, nrows, ncols, P, mh, bar, out, B);
}

// Round 9
// 583.827 us; speedup vs baseline: 1.0552x; 1.0552x over previous
//
#include <hip/hip_runtime.h>
#include <math.h>

// Persistent Sinkhorn R9 (= R8 fixed): non-temporal out/m accesses to keep
// mh L3-resident. R8 failed to compile: __builtin_nontemporal_* rejects
// HIP_vector_type (float4 class). Use clang ext_vector_type(4) float (f4),
// layout-compatible, for all NT paths.
//
// R7 post-mortem: cutting 30% of VALU work left time unchanged (296->306us,
// VALUBusy 37->24%) -> NOT issue-bound. FETCH still 512MB: the ~64MB active
// mh set is re-fetched from HBM every pass because ~370MB of streaming
// writes (out zero-fill + final + mh + P) evict it from L3.
//
// R9: cache-pollution control.
//  - ALL out stores -> __builtin_nontemporal_store (read-never data).
//  - F0's m loads  -> __builtin_nontemporal_load  (read-once data).
//  - mh loads/stores stay CACHED (the only data with reuse).
// L3 (256MB) then retains mh (~64MB active) across all 10 passes.
//
// Carried (proven R3-R7): per-batch monotonic barrier w/ relaxed agent
// atomics + vmcnt(0) drain; sc0sc1-coherent P only; 1 barrier/iter;
// plain-sum col partials via exp reuse; conflict-free pbuf[4][64][17];
// coalesced P layout; dual-row ILP; no-max-shift log2-domain lse;
// early zero-fill + degenerate-batch exit; fp16 final.
//
// ws: bar@0 (4KB) | P@1MB (2 x 4MB) | mh@16MB (128MB). ws >= 1GB.

#define BIGNEG (-1e30f)
#define LOG2E 1.44269504f
typedef _Float16 h16;
struct alignas(16) h8 { h16 h[8]; };
typedef float f4 __attribute__((ext_vector_type(4)));  // NT-compatible vec4

#define NN 1024
#define MM 1024
#define NBLK 16  // blocks per batch

__device__ __forceinline__ float wave_sum64(float v) {
#pragma unroll
    for (int o = 32; o > 0; o >>= 1) v += __shfl_xor(v, o, 64);
    return v;
}

__device__ __forceinline__ float ld_coh(const float* p) {
    return __hip_atomic_load(p, __ATOMIC_RELAXED, __HIP_MEMORY_SCOPE_AGENT);
}
__device__ __forceinline__ void st_coh(float* p, float v) {
    __hip_atomic_store(p, v, __ATOMIC_RELAXED, __HIP_MEMORY_SCOPE_AGENT);
}

__global__ void zero_bar(unsigned* bar, int n) {
    const int i = blockIdx.x * blockDim.x + threadIdx.x;
    if (i < n) bar[i] = 0;
}

// Monotonic per-batch barrier (proven R3-R7). Relaxed atomics; each wave
// drains its own sc1 stores to the coherence point before arriving.
#define BATCH_BAR()                                                            \
    do {                                                                       \
        asm volatile("s_waitcnt vmcnt(0)" ::: "memory");                       \
        __syncthreads();                                                       \
        ++phase;                                                               \
        if (threadIdx.x == 0) {                                                \
            __hip_atomic_fetch_add(ctr, 1u, __ATOMIC_RELAXED,                  \
                                   __HIP_MEMORY_SCOPE_AGENT);                  \
            while (__hip_atomic_load(ctr, __ATOMIC_RELAXED,                    \
                                     __HIP_MEMORY_SCOPE_AGENT) <               \
                   (unsigned)(phase * NBLK))                                   \
                __builtin_amdgcn_s_sleep(8);                                   \
        }                                                                      \
        __syncthreads();                                                       \
        asm volatile("" ::: "memory");                                         \
    } while (0)

// No-shift lse over 16 per-lane log2-domain values: S = sum 2^z (wave-wide),
// u2 = -log2(S); col partials cs[e] += 2^z[e] / S. Safe: |z| << 126.
__device__ __forceinline__ void sum16(const float* z, float* cs, float& u2) {
    float p[16], s = 0.f;
#pragma unroll
    for (int e = 0; e < 16; ++e) {
        p[e] = __builtin_amdgcn_exp2f(z[e]);
        s += p[e];
    }
    s = wave_sum64(s);
    const float rs = __builtin_amdgcn_rcpf(s);
#pragma unroll
    for (int e = 0; e < 16; ++e) cs[e] += p[e] * rs;
    u2 = -__builtin_amdgcn_logf(s);  // v_log_f32 = log2
}

__device__ __forceinline__ void nt_store4(float* p, f4 v) {
    __builtin_nontemporal_store(v, reinterpret_cast<f4*>(p));
}
__device__ __forceinline__ f4 nt_load4(const float* p) {
    return __builtin_nontemporal_load(reinterpret_cast<const f4*>(p));
}

__global__ __launch_bounds__(256, 4) void sinkhorn_fused(
    const float* __restrict__ m, const int* __restrict__ nrows,
    const int* __restrict__ ncols, float* __restrict__ P,
    h16* __restrict__ mh, unsigned* __restrict__ bar, float* __restrict__ out,
    int B) {
    const int sub = blockIdx.x & (NBLK - 1);
    const int b = blockIdx.x >> 4;
    const int w = threadIdx.x >> 6;
    const int lane = threadIdx.x & 63;
    const int wid = sub * 4 + w;  // wave id within batch [0,64)
    const int tid = threadIdx.x;
    const int nr = nrows[b];
    const int nc = ncols[b];
    unsigned* ctr = bar + (size_t)b * 16;
    int phase = 0;

    __shared__ float pbuf[4][64][17];  // 17KB padded: conflict-free merge
    __shared__ float vloc[MM];         // 4KB full v (log2), block-local
    __shared__ float uloc[NN];         // 4KB u (log2) for this block's rows

    const size_t mbo = (size_t)b * NN * MM;
    const f4 z4 = {0.f, 0.f, 0.f, 0.f};

    // ---- degenerate batches: all-zero output, exit (no barrier contact) ----
    if (nr == 0 || nc == 0) {
        for (int row = wid; row < NN; row += 64) {
            float* orow = out + mbo + (size_t)row * MM + lane * 8;
            nt_store4(orow, z4);
            nt_store4(orow + 4, z4);
            nt_store4(orow + 512, z4);
            nt_store4(orow + 516, z4);
        }
        return;
    }

    const size_t Psz = (size_t)B * NBLK * MM;  // one parity buffer (4MB)
    float* Pw0 = P + (size_t)b * NBLK * MM + (size_t)sub * MM;
    const float* Pr0 = P + (size_t)b * NBLK * MM;

    float cs[16];
#pragma unroll
    for (int e = 0; e < 16; ++e) cs[e] = 0.f;

    // ---- F0: fp32 m (NT) -> fp16 mh2=m*log2e, u1, col partial sums ----
    {
        float mk[16];
#pragma unroll
        for (int e = 0; e < 16; ++e) {
            const int col = lane * 8 + (e >> 3) * 512 + (e & 7);
            mk[e] = (col < nc) ? 0.f : BIGNEG;
        }
        int row = wid;
        f4 A0, A1, A2, A3;
        if (row < nr) {
            const float* rp = m + mbo + (size_t)row * MM + lane * 8;
            A0 = nt_load4(rp);
            A1 = nt_load4(rp + 4);
            A2 = nt_load4(rp + 512);
            A3 = nt_load4(rp + 516);
        }
        while (row < nr) {
            const int nx = row + 64;
            f4 N0, N1, N2, N3;
            if (nx < nr) {  // prefetch next row while reducing current
                const float* rq = m + mbo + (size_t)nx * MM + lane * 8;
                N0 = nt_load4(rq);
                N1 = nt_load4(rq + 4);
                N2 = nt_load4(rq + 512);
                N3 = nt_load4(rq + 516);
            }
            float zs[16], zr[16];
            *reinterpret_cast<f4*>(&zs[0]) = A0;
            *reinterpret_cast<f4*>(&zs[4]) = A1;
            *reinterpret_cast<f4*>(&zs[8]) = A2;
            *reinterpret_cast<f4*>(&zs[12]) = A3;
#pragma unroll
            for (int e = 0; e < 16; ++e) {
                zs[e] *= LOG2E;          // log2 domain
                zr[e] = zs[e] + mk[e];   // masked copy for the reduce
            }
            h8 hv0, hv1;
#pragma unroll
            for (int e = 0; e < 8; ++e) hv0.h[e] = (h16)zs[e];
#pragma unroll
            for (int e = 0; e < 8; ++e) hv1.h[e] = (h16)zs[8 + e];
            h16* rh = mh + mbo + (size_t)row * MM + lane * 8;
            *reinterpret_cast<h8*>(rh) = hv0;        // cached: reused 10x
            *reinterpret_cast<h8*>(rh + 512) = hv1;
            float u;
            sum16(zr, cs, u);
            if (lane == 0) uloc[row] = u;
            A0 = N0; A1 = N1; A2 = N2; A3 = N3;
            row = nx;
        }
    }

    // ---- early zero-fill of invalid rows (NT; overlaps other batches) ----
    for (int row = nr + wid; row < NN; row += 64) {
        float* orow = out + mbo + (size_t)row * MM + lane * 8;
        nt_store4(orow, z4);
        nt_store4(orow + 4, z4);
        nt_store4(orow + 512, z4);
        nt_store4(orow + 516, z4);
    }

    for (int t = 1; t <= 10; ++t) {
        // ---- merge 4 waves' cs -> block partial -> coherent P[t&1] ----
#pragma unroll
        for (int e = 0; e < 16; ++e) pbuf[w][lane][e] = cs[e];
        __syncthreads();
        {
            float* Pw = Pw0 + (size_t)(t & 1) * Psz;
#pragma unroll
            for (int q = 0; q < 4; ++q) {
                const int col = tid + q * 256;  // coalesced
                const int ls = (col >> 3) & 63;
                const int ei = ((col >> 9) << 3) | (col & 7);
                const float sum = pbuf[0][ls][ei] + pbuf[1][ls][ei] +
                                  pbuf[2][ls][ei] + pbuf[3][ls][ei];
                st_coh(Pw + col, sum);
            }
        }

        BATCH_BAR();  // all 16 blocks' partials at coherence point

        // ---- redundant local finalize: full v (log2) for all 1024 cols ----
        {
            const float* Pr = Pr0 + (size_t)(t & 1) * Psz;
#pragma unroll
            for (int q = 0; q < 4; ++q) {
                const int col = tid + q * 256;  // coalesced
                float CS = 0.f;
#pragma unroll
                for (int s16 = 0; s16 < NBLK; ++s16)
                    CS += ld_coh(Pr + s16 * MM + col);
                const float vp = (t == 1) ? 0.f : vloc[col];
                const float vn = vp - __log2f(CS);  // CS=0 -> +inf -> clamp
                vloc[col] = fminf(fmaxf(vn, BIGNEG), 1e30f);
            }
        }
        __syncthreads();  // vloc ready for all waves
        if (t == 10) break;

        // ---- row pass: u_{t+1} = -lse2_j(mh2+v_t); col sums for v_{t+1} ----
        float vvm[16];
        {
            float tmp[16];
            *reinterpret_cast<f4*>(&tmp[0]) =
                *reinterpret_cast<const f4*>(&vloc[lane * 8]);
            *reinterpret_cast<f4*>(&tmp[4]) =
                *reinterpret_cast<const f4*>(&vloc[lane * 8 + 4]);
            *reinterpret_cast<f4*>(&tmp[8]) =
                *reinterpret_cast<const f4*>(&vloc[lane * 8 + 512]);
            *reinterpret_cast<f4*>(&tmp[12]) =
                *reinterpret_cast<const f4*>(&vloc[lane * 8 + 516]);
#pragma unroll
            for (int e = 0; e < 16; ++e) {
                const int col = lane * 8 + (e >> 3) * 512 + (e & 7);
                vvm[e] = (col < nc) ? tmp[e] : BIGNEG;
            }
        }
#pragma unroll
        for (int e = 0; e < 16; ++e) cs[e] = 0.f;
        {
            int row = wid;
            // dual-row: two independent chains, 4 loads issued first
            while (row + 64 < nr) {
                const h16* r0 = mh + mbo + (size_t)row * MM + lane * 8;
                const h16* r1 = r0 + (size_t)64 * MM;
                const h8 a0 = *reinterpret_cast<const h8*>(r0);
                const h8 a1 = *reinterpret_cast<const h8*>(r0 + 512);
                const h8 b0 = *reinterpret_cast<const h8*>(r1);
                const h8 b1 = *reinterpret_cast<const h8*>(r1 + 512);
                float z0[16], z1[16];
#pragma unroll
                for (int e = 0; e < 8; ++e) {
                    z0[e] = (float)a0.h[e] + vvm[e];
                    z0[8 + e] = (float)a1.h[e] + vvm[8 + e];
                    z1[e] = (float)b0.h[e] + vvm[e];
                    z1[8 + e] = (float)b1.h[e] + vvm[8 + e];
                }
                float u0, u1;
                sum16(z0, cs, u0);
                sum16(z1, cs, u1);
                if (lane == 0) { uloc[row] = u0; uloc[row + 64] = u1; }
                row += 128;
            }
            if (row < nr) {
                const h16* r0 = mh + mbo + (size_t)row * MM + lane * 8;
                const h8 a0 = *reinterpret_cast<const h8*>(r0);
                const h8 a1 = *reinterpret_cast<const h8*>(r0 + 512);
                float z0[16];
#pragma unroll
                for (int e = 0; e < 8; ++e) {
                    z0[e] = (float)a0.h[e] + vvm[e];
                    z0[8 + e] = (float)a1.h[e] + vvm[8 + e];
                }
                float u0;
                sum16(z0, cs, u0);
                if (lane == 0) uloc[row] = u0;
            }
        }
    }

    // ---- final: out = 2^(mh2 + u10 + v10), valid rows only (NT stores) ----
    {
        float vvm[16];
        float tmp[16];
        *reinterpret_cast<f4*>(&tmp[0]) =
            *reinterpret_cast<const f4*>(&vloc[lane * 8]);
        *reinterpret_cast<f4*>(&tmp[4]) =
            *reinterpret_cast<const f4*>(&vloc[lane * 8 + 4]);
        *reinterpret_cast<f4*>(&tmp[8]) =
            *reinterpret_cast<const f4*>(&vloc[lane * 8 + 512]);
        *reinterpret_cast<f4*>(&tmp[12]) =
            *reinterpret_cast<const f4*>(&vloc[lane * 8 + 516]);
#pragma unroll
        for (int e = 0; e < 16; ++e) {
            const int col = lane * 8 + (e >> 3) * 512 + (e & 7);
            vvm[e] = (col < nc) ? tmp[e] : BIGNEG;
        }
        for (int row = wid; row < nr; row += 64) {
            float* orow = out + mbo + (size_t)row * MM + lane * 8;
            const float ui = uloc[row];
            const h16* rh = mh + mbo + (size_t)row * MM + lane * 8;
            const h8 h0 = *reinterpret_cast<const h8*>(rh);
            const h8 h1 = *reinterpret_cast<const h8*>(rh + 512);
            float r[16];
#pragma unroll
            for (int e = 0; e < 8; ++e) {
                r[e] = __builtin_amdgcn_exp2f((float)h0.h[e] + ui + vvm[e]);
                r[8 + e] =
                    __builtin_amdgcn_exp2f((float)h1.h[e] + ui + vvm[8 + e]);
            }
            nt_store4(orow, *reinterpret_cast<f4*>(&r[0]));
            nt_store4(orow + 4, *reinterpret_cast<f4*>(&r[4]));
            nt_store4(orow + 512, *reinterpret_cast<f4*>(&r[8]));
            nt_store4(orow + 516, *reinterpret_cast<f4*>(&r[12]));
        }
    }
}

extern "C" void kernel_launch(void* const* d_in, const int* in_sizes, int n_in,
                              void* d_out, int out_size, void* d_ws,
                              size_t ws_size, hipStream_t stream) {
    const float* m = (const float*)d_in[0];
    const int* nrows = (const int*)d_in[1];
    const int* ncols = (const int*)d_in[2];
    const int B = in_sizes[1];

    char* ws = (char*)d_ws;
    unsigned* bar = (unsigned*)ws;          // 4KB
    float* P = (float*)(ws + (1u << 20));   // 2 x 4MB
    h16* mh = (h16*)(ws + (16u << 20));     // 128MB
    float* out = (float*)d_out;

    const int nbar = B * 16;
    zero_bar<<<dim3((nbar + 255) / 256), dim3(256), 0, stream>>>(bar, nbar);

    sinkhorn_fused<<<dim3(B * NBLK), dim3(256), 0, stream>>>(
        m, nrows, ncols, P, mh, bar, out, B);
}